// Round 5
// baseline (203.776 us; speedup 1.0000x reference)
//
#include <hip/hip_runtime.h>

// GCN layer: out = ReLU(BN(GCNConv(x) + x@skip_W))
// R23: eliminate the `pre` intermediate (was 25.6MB write + 25.6MB read).
//   GEMM compute is ~1.4us MFMA and A (12.8MB) is L3-resident after k_agg,
//   so recompute instead of store:
//   - k_gemm_stats: R22 gemm minus stores; BN sum/sumsq only.
//   - k_gemm_apply: recompute MFMA, apply scaleshift+ReLU in-register,
//     guarded float4 stores straight to fp32 out (51.2MB HBM floor ~8.5us).
//   pre buffer removed; xd8 gets its own slot. absmax path now exact f32
//   (no bf16 roundtrip of pre). Kernel count stays 8.
// Rest identical to R22 (197.2us).

typedef unsigned short ushort;
typedef __bf16 bf16x8 __attribute__((ext_vector_type(8)));
typedef float f32x4 __attribute__((ext_vector_type(4)));
typedef float f32x2 __attribute__((ext_vector_type(2)));

constexpr int N_NODES = 100000;
constexpr int N_PAD   = 100096;                  // 782*128
constexpr int E_EDGES = 1600000;

constexpr int BUCK_SHIFT = 7;                    // 128 nodes per bucket
constexpr int NBUCK   = (N_NODES + 127) / 128;   // 782
constexpr int NBUCK_P = 784;
constexpr int CHUNK   = 8192;
constexpr int NCHUNK  = (E_EDGES + CHUNK - 1) / CHUNK;  // 196
constexpr int GH_STRIDE = 200;
constexpr int SORT_CAP = 4096;
constexpr int GG      = 256;                     // gemm grid

// ws layout (4-byte element offsets) — audited for R23:
constexpr size_t OFF_SCALE  = 0;                 // 256 floats
constexpr size_t OFF_DINV   = 256;               // 100000 -> ends 100256
constexpr size_t OFF_ROWPTR = 100352;            // 100001 ints -> ends 200353
constexpr size_t OFF_BASE   = 200480;            // 783 ints -> ends 201263
constexpr size_t OFF_GHIST  = 201280;            // 784*200 -> ends 358080
constexpr size_t OFF_BINNED = 358080;            // 1.6M -> ends 1958080
constexpr size_t OFF_PART   = OFF_BINNED;        // aliases binned (dead after agg)
constexpr size_t OFF_A      = 1958080;           // N_PAD*128 ushort /2 -> ends 8364224
constexpr size_t OFF_XD8    = 8364224;           // N_PAD*16 uint -> ends 9965760
constexpr size_t OFF_BT     = 9965760;           // 16384 ushort /2 -> ends 9973952
constexpr size_t OFF_TICK   = 9973952;           // 2 uints

static __device__ __forceinline__ ushort f2bf(float f) {
    union { float f; unsigned u; } v; v.f = f;
    unsigned r = v.u + 0x7FFFu + ((v.u >> 16) & 1u);  // RNE
    return (ushort)(r >> 16);
}
static __device__ __forceinline__ unsigned pack_fp8x4(float a, float b, float c, float d) {
    int r = 0;
    r = __builtin_amdgcn_cvt_pk_fp8_f32(a, b, r, false);
    r = __builtin_amdgcn_cvt_pk_fp8_f32(c, d, r, true);
    return (unsigned)r;
}

// ---- hist (blocks 0..NCHUNK-1, transposed write) + Bt prep + ticket init ----
__global__ __launch_bounds__(256) void k_hist(const int* __restrict__ col,
                                              int* __restrict__ gh_t,
                                              const float* __restrict__ W,
                                              const float* __restrict__ skipW,
                                              ushort* __restrict__ Bt,
                                              unsigned* __restrict__ tick) {
    int c = blockIdx.x, t = threadIdx.x;
    if (c >= NCHUNK) {  // prep: Bt[n][k] = bf16(B[k][n]); zero ticket
        int idx = (c - NCHUNK) * 256 + t;
        if (c == NCHUNK && t < 2) tick[t] = 0u;
        int k = idx >> 7, n = idx & 127;
        float v = (k < 64) ? W[k * 128 + n] : skipW[(k - 64) * 128 + n];
        Bt[n * 128 + k] = f2bf(v);
        return;
    }
    __shared__ int h[NBUCK_P];
    for (int b = t; b < NBUCK_P; b += 256) h[b] = 0;
    __syncthreads();
    const int4* col4 = (const int4*)col;
    int g0 = c * (CHUNK / 4);
#pragma unroll
    for (int i = 0; i < CHUNK / 1024; ++i) {
        int g4 = g0 + i * 256 + t;
        if (g4 * 4 + 3 < E_EDGES) {
            int4 cc = col4[g4];
            atomicAdd(&h[cc.x >> BUCK_SHIFT], 1);
            atomicAdd(&h[cc.y >> BUCK_SHIFT], 1);
            atomicAdd(&h[cc.z >> BUCK_SHIFT], 1);
            atomicAdd(&h[cc.w >> BUCK_SHIFT], 1);
        } else {
#pragma unroll
            for (int j = 0; j < 4; ++j) {
                int e = g4 * 4 + j;
                if (e < E_EDGES) atomicAdd(&h[col[e] >> BUCK_SHIFT], 1);
            }
        }
    }
    __syncthreads();
    for (int b = t; b < NBUCK_P; b += 256) gh_t[(size_t)b * GH_STRIDE + c] = h[b];
}

// ---- fused: wave-per-bucket chunk scan + (last block) base exclusive scan ----
__global__ __launch_bounds__(256) void k_scan(int* __restrict__ gh_t,
                                              int* __restrict__ base,
                                              int* __restrict__ rowptr,
                                              unsigned* __restrict__ tick) {
    __shared__ int wtot[4];
    __shared__ int amlast;
    int w = threadIdx.x >> 6, l = threadIdx.x & 63;
    int b = blockIdx.x * 4 + w;          // 196 blocks x 4 waves = 784 (== NBUCK_P)
    int* rowp = gh_t + (size_t)b * GH_STRIDE;
    int carry = 0;
#pragma unroll
    for (int i = 0; i < 4; ++i) {        // 4*64 = 256 >= NCHUNK
        int idx = i * 64 + l;
        int v = (idx < NCHUNK) ? rowp[idx] : 0;
        int orig = v;
#pragma unroll
        for (int d = 1; d < 64; d <<= 1) {
            int o = __shfl_up(v, d);
            if (l >= d) v += o;
        }
        if (idx < NCHUNK) rowp[idx] = carry + v - orig;  // exclusive
        carry += __shfl(v, 63);
    }
    // publish bucket total via device-scope atomic (LLC-coherent)
    if (l == 0 && b < NBUCK) atomicExch(&base[b], carry);
    __syncthreads();
    if (threadIdx.x == 0)
        amlast = (atomicAdd(tick + 0, 1u) == (unsigned)(gridDim.x - 1)) ? 1 : 0;
    __syncthreads();
    if (!amlast) return;

    // last block: exclusive scan of base[0..NBUCK-1], blocked 4 per thread
    int t = threadIdx.x;
    int i0 = t * 4;
    int v0 = (i0 + 0 < NBUCK) ? atomicAdd(&base[i0 + 0], 0) : 0;
    int v1 = (i0 + 1 < NBUCK) ? atomicAdd(&base[i0 + 1], 0) : 0;
    int v2 = (i0 + 2 < NBUCK) ? atomicAdd(&base[i0 + 2], 0) : 0;
    int v3 = (i0 + 3 < NBUCK) ? atomicAdd(&base[i0 + 3], 0) : 0;
    int s = v0 + v1 + v2 + v3;
    int incl = s;
#pragma unroll
    for (int d = 1; d < 64; d <<= 1) {
        int o = __shfl_up(incl, d);
        if (l >= d) incl += o;
    }
    if (l == 63) wtot[w] = incl;
    __syncthreads();
    int wpre = 0;
    for (int ww = 0; ww < w; ++ww) wpre += wtot[ww];
    int excl = wpre + incl - s;
    if (i0 + 0 < NBUCK) base[i0 + 0] = excl;
    if (i0 + 1 < NBUCK) base[i0 + 1] = excl + v0;
    if (i0 + 2 < NBUCK) base[i0 + 2] = excl + v0 + v1;
    if (i0 + 3 < NBUCK) base[i0 + 3] = excl + v0 + v1 + v2;
    if (t == 255) {
        int total = wpre + incl;
        base[NBUCK] = total;             // bucket sentinel
        rowptr[N_NODES] = total;
    }
}

// ---- scatter edges into bucket-contiguous array (packed), int4 reads ----
__global__ __launch_bounds__(256) void k_scatter_bin(const int* __restrict__ row,
                                                     const int* __restrict__ col,
                                                     const int* __restrict__ gh_t,
                                                     const int* __restrict__ base,
                                                     unsigned int* __restrict__ binned) {
    __shared__ int cur[NBUCK_P];
    int c = blockIdx.x, t = threadIdx.x;
    for (int b = t; b < NBUCK_P; b += 256) {
        int bb = (b < NBUCK) ? base[b] : 0;
        cur[b] = bb + gh_t[(size_t)b * GH_STRIDE + c];
    }
    __syncthreads();
    const int4* col4 = (const int4*)col;
    const int4* row4 = (const int4*)row;
    int g0 = c * (CHUNK / 4);
#pragma unroll
    for (int i = 0; i < CHUNK / 1024; ++i) {
        int g4 = g0 + i * 256 + t;
        if (g4 * 4 + 3 < E_EDGES) {
            int4 cc = col4[g4];
            int4 rr = row4[g4];
            int p;
            p = atomicAdd(&cur[cc.x >> BUCK_SHIFT], 1);
            binned[p] = ((unsigned)(cc.x & 127) << 17) | (unsigned)rr.x;
            p = atomicAdd(&cur[cc.y >> BUCK_SHIFT], 1);
            binned[p] = ((unsigned)(cc.y & 127) << 17) | (unsigned)rr.y;
            p = atomicAdd(&cur[cc.z >> BUCK_SHIFT], 1);
            binned[p] = ((unsigned)(cc.z & 127) << 17) | (unsigned)rr.z;
            p = atomicAdd(&cur[cc.w >> BUCK_SHIFT], 1);
            binned[p] = ((unsigned)(cc.w & 127) << 17) | (unsigned)rr.w;
        } else {
#pragma unroll
            for (int j = 0; j < 4; ++j) {
                int e = g4 * 4 + j;
                if (e < E_EDGES) {
                    int d = col[e], s = row[e];
                    int p = atomicAdd(&cur[d >> BUCK_SHIFT], 1);
                    binned[p] = ((unsigned)(d & 127) << 17) | (unsigned)s;
                }
            }
        }
    }
}

// ---- per-bucket counting sort -> csr, rowptr, dinv; fused fp8 cast + A x-half ----
__global__ __launch_bounds__(256) void k_sortbucket(unsigned int* __restrict__ binned,
                                                    const int* __restrict__ base,
                                                    int* __restrict__ rowptr,
                                                    float* __restrict__ dinv,
                                                    const float* __restrict__ x,
                                                    unsigned* __restrict__ xd8,
                                                    ushort* __restrict__ A) {
    __shared__ unsigned int ebuf[SORT_CAP];
    __shared__ int sbuf[SORT_CAP];
    __shared__ int lcnt[128];
    __shared__ int lptr[128];
    __shared__ float ldinv[128];
    __shared__ int wsum[2];
    int b = blockIdx.x, t = threadIdx.x;
    int i0 = base[b], i1 = base[b + 1];
    int cnt = i1 - i0;
    if (cnt > SORT_CAP) cnt = SORT_CAP;
    int n0 = b << BUCK_SHIFT;
    int nn = min(128, N_NODES - n0);

    for (int k = t; k < cnt; k += 256) ebuf[k] = binned[i0 + k];
    if (t < 128) lcnt[t] = 0;
    __syncthreads();
    for (int k = t; k < cnt; k += 256) atomicAdd(&lcnt[ebuf[k] >> 17], 1);
    __syncthreads();

    // 128-wide exclusive scan via 2-wave shfl
    int myc = 0, val = 0;
    if (t < 128) {
        myc = lcnt[t];
        val = myc;
#pragma unroll
        for (int d = 1; d < 64; d <<= 1) {
            int o = __shfl_up(val, d);
            if ((t & 63) >= d) val += o;
        }
        if ((t & 63) == 63) wsum[t >> 6] = val;
    }
    __syncthreads();
    if (t < 128) {
        if (t >= 64) val += wsum[0];
        int excl = val - myc;
        lptr[t] = excl;
        float dv = rsqrtf((float)myc + 1.0f);  // +1 self loop
        ldinv[t] = dv;
        if (t < nn) {
            rowptr[n0 + t] = i0 + excl;
            dinv[n0 + t] = dv;
        }
    }
    __syncthreads();
    for (int k = t; k < cnt; k += 256) {
        unsigned int e = ebuf[k];
        int j = (int)(e >> 17);
        int p = atomicAdd(&lptr[j], 1);
        sbuf[p] = (int)(e & 0x1FFFF);
    }
    __syncthreads();
    for (int k = t; k < cnt; k += 256) binned[i0 + k] = (unsigned int)sbuf[k];

    // fused cast: this bucket's 128 node rows -> xd8 (fp8 of x*dinv)
    //             + A cols 64..127 = bf16(raw x) (zero-padded rows)
#pragma unroll
    for (int it = 0; it < 8; ++it) {
        int idx = it * 256 + t;          // 0..2047
        int nl = idx >> 4, q = idx & 15;
        int c = n0 + nl;
        unsigned w8 = 0;
        ushort4 xb = {0, 0, 0, 0};
        if (nl < nn) {
            float4 v = ((const float4*)x)[(size_t)c * 16 + q];
            float d = ldinv[nl];
            w8 = pack_fp8x4(v.x * d, v.y * d, v.z * d, v.w * d);
            xb.x = f2bf(v.x); xb.y = f2bf(v.y); xb.z = f2bf(v.z); xb.w = f2bf(v.w);
        }
        xd8[(size_t)c * 16 + q] = w8;
        ((ushort4*)A)[(size_t)c * 32 + 16 + q] = xb;   // cols 64..127
    }
}

// ---- aggregation: 16 lanes per node; fp8 gather; writes A cols 0..63 ----
__global__ __launch_bounds__(256) void k_agg(const unsigned* __restrict__ xd8,
                                             const float* __restrict__ dinv,
                                             const int* __restrict__ rowptr,
                                             const unsigned int* __restrict__ csr,
                                             ushort* __restrict__ A) {
    int t = blockIdx.x * blockDim.x + threadIdx.x;
    if (t >= N_PAD * 16) return;
    int c = t >> 4;
    int q = t & 15;
    if (c >= N_NODES) {
        ushort4 z = {0, 0, 0, 0};
        ((ushort4*)A)[(size_t)c * 32 + q] = z;
        return;
    }
    float dc = dinv[c];
    float4 acc;
    {
        unsigned w = xd8[t];
        f32x2 lo = __builtin_amdgcn_cvt_pk_f32_fp8((int)w, false);
        f32x2 hi = __builtin_amdgcn_cvt_pk_f32_fp8((int)w, true);
        acc.x = lo.x; acc.y = lo.y; acc.z = hi.x; acc.w = hi.y;
    }
    int i0 = rowptr[c], i1 = rowptr[c + 1];
    int i = i0;
    for (; i + 8 <= i1; i += 8) {
        int s[8];
#pragma unroll
        for (int k = 0; k < 8; ++k) s[k] = (int)csr[i + k];
        unsigned w[8];
#pragma unroll
        for (int k = 0; k < 8; ++k) w[k] = xd8[s[k] * 16 + q];
#pragma unroll
        for (int k = 0; k < 8; ++k) {
            f32x2 lo = __builtin_amdgcn_cvt_pk_f32_fp8((int)w[k], false);
            f32x2 hi = __builtin_amdgcn_cvt_pk_f32_fp8((int)w[k], true);
            acc.x += lo.x; acc.y += lo.y; acc.z += hi.x; acc.w += hi.y;
        }
    }
    for (; i < i1; ++i) {
        unsigned w = xd8[(int)csr[i] * 16 + q];
        f32x2 lo = __builtin_amdgcn_cvt_pk_f32_fp8((int)w, false);
        f32x2 hi = __builtin_amdgcn_cvt_pk_f32_fp8((int)w, true);
        acc.x += lo.x; acc.y += lo.y; acc.z += hi.x; acc.w += hi.y;
    }
    ushort4 o;
    o.x = f2bf(acc.x * dc); o.y = f2bf(acc.y * dc);
    o.z = f2bf(acc.z * dc); o.w = f2bf(acc.w * dc);
    ((ushort4*)A)[(size_t)c * 32 + q] = o;             // cols 0..63
}

// ---- GEMM pass 1: BN sum/sumsq only (no stores). A is L3-resident. ----
// Persistent: GG blocks x 512 thr / 8 waves; wave (wm,wn) = rows [wm*64,+64) x
// cols [wn*32,+32). Swapped mfma(bf, af): lane holds 4 consecutive output cols.
__global__ __launch_bounds__(512, 2) void k_gemm_stats(const ushort* __restrict__ A,
                                                       const ushort* __restrict__ Bt,
                                                       float* __restrict__ partial) {
    __shared__ float sred[128];
    __shared__ float qred[128];
    int tid = threadIdx.x;
    int wave = tid >> 6, lane = tid & 63;
    int wm = wave >> 2, wn = wave & 3;
    int l15 = lane & 15, quad = lane >> 4;
    int col0 = wn * 32;

    if (tid < 128) { sred[tid] = 0.f; qred[tid] = 0.f; }
    __syncthreads();

    bf16x8 bf_[4][2];
#pragma unroll
    for (int kc = 0; kc < 4; ++kc)
#pragma unroll
        for (int jc = 0; jc < 2; ++jc)
            bf_[kc][jc] = *(const bf16x8*)&Bt[(size_t)(col0 + jc * 16 + l15) * 128 + kc * 32 + quad * 8];

    float lsum[8] = {0.f, 0.f, 0.f, 0.f, 0.f, 0.f, 0.f, 0.f};
    float lsq[8]  = {0.f, 0.f, 0.f, 0.f, 0.f, 0.f, 0.f, 0.f};

    for (int ci = blockIdx.x; ci < NBUCK; ci += GG) {
        int row0 = ci * 128 + wm * 64;
        bf16x8 af[4][4];
#pragma unroll
        for (int kc = 0; kc < 4; ++kc)
#pragma unroll
            for (int ir = 0; ir < 4; ++ir)
                af[kc][ir] = *(const bf16x8*)&A[(size_t)(row0 + ir * 16 + l15) * 128 + kc * 32 + quad * 8];

        f32x4 acc[4][2];
#pragma unroll
        for (int ir = 0; ir < 4; ++ir)
#pragma unroll
            for (int jc = 0; jc < 2; ++jc) acc[ir][jc] = (f32x4){0.f, 0.f, 0.f, 0.f};

#pragma unroll
        for (int kc = 0; kc < 4; ++kc)
#pragma unroll
            for (int ir = 0; ir < 4; ++ir)
#pragma unroll
                for (int jc = 0; jc < 2; ++jc)
                    acc[ir][jc] = __builtin_amdgcn_mfma_f32_16x16x32_bf16(
                        bf_[kc][jc], af[kc][ir], acc[ir][jc], 0, 0, 0);

#pragma unroll
        for (int ir = 0; ir < 4; ++ir) {
            int row = row0 + ir * 16 + l15;
            if (row < N_NODES) {
#pragma unroll
                for (int jc = 0; jc < 2; ++jc)
#pragma unroll
                    for (int r = 0; r < 4; ++r) {
                        float v = acc[ir][jc][r];
                        lsum[jc * 4 + r] += v;
                        lsq[jc * 4 + r]  += v * v;
                    }
            }
        }
    }

    // reduce over the 16 row-lanes (l15), then LDS atomics, then global partial
#pragma unroll
    for (int m = 1; m < 16; m <<= 1) {
#pragma unroll
        for (int i = 0; i < 8; ++i) {
            lsum[i] += __shfl_xor(lsum[i], m);
            lsq[i]  += __shfl_xor(lsq[i], m);
        }
    }
    if (l15 == 0) {
#pragma unroll
        for (int jc = 0; jc < 2; ++jc)
#pragma unroll
            for (int r = 0; r < 4; ++r) {
                int c = col0 + jc * 16 + quad * 4 + r;
                atomicAdd(&sred[c], lsum[jc * 4 + r]);
                atomicAdd(&qred[c], lsq[jc * 4 + r]);
            }
    }
    __syncthreads();
    if (tid < 128) {
        partial[(size_t)blockIdx.x * 256 + tid]       = sred[tid];
        partial[(size_t)blockIdx.x * 256 + 128 + tid] = qred[tid];
    }
}

// ---- reduce GG partials -> scale/shift (one block per output column) ----
__global__ __launch_bounds__(256) void k_reduce(const float* __restrict__ partial,
                                                const float* __restrict__ gamma,
                                                const float* __restrict__ beta,
                                                float* __restrict__ scaleshift) {
    __shared__ float ls[256], lq[256];
    int j = blockIdx.x;   // 0..127
    int t = threadIdx.x;
    float s = 0.f, q = 0.f;
    for (int p = t; p < GG; p += 256) {
        s += partial[(size_t)p * 256 + j];
        q += partial[(size_t)p * 256 + 128 + j];
    }
    ls[t] = s; lq[t] = q;
    __syncthreads();
#pragma unroll
    for (int off = 128; off > 0; off >>= 1) {
        if (t < off) { ls[t] += ls[t + off]; lq[t] += lq[t + off]; }
        __syncthreads();
    }
    if (t == 0) {
        float mean = ls[0] * (1.0f / N_NODES);
        float var  = lq[0] * (1.0f / N_NODES) - mean * mean;
        float sc   = gamma[j] * rsqrtf(var + 1e-5f);
        scaleshift[j]       = sc;
        scaleshift[128 + j] = beta[j] - mean * sc;
    }
}

// ---- GEMM pass 2: recompute + BN apply + ReLU -> fp32 out (float4 stores) ----
__global__ __launch_bounds__(512, 2) void k_gemm_apply(const ushort* __restrict__ A,
                                                       const ushort* __restrict__ Bt,
                                                       const float* __restrict__ ss,
                                                       float* __restrict__ out) {
    int tid = threadIdx.x;
    int wave = tid >> 6, lane = tid & 63;
    int wm = wave >> 2, wn = wave & 3;
    int l15 = lane & 15, quad = lane >> 4;
    int col0 = wn * 32;

    bf16x8 bf_[4][2];
#pragma unroll
    for (int kc = 0; kc < 4; ++kc)
#pragma unroll
        for (int jc = 0; jc < 2; ++jc)
            bf_[kc][jc] = *(const bf16x8*)&Bt[(size_t)(col0 + jc * 16 + l15) * 128 + kc * 32 + quad * 8];

    float4 sc4[2], sh4[2];
#pragma unroll
    for (int jc = 0; jc < 2; ++jc) {
        sc4[jc] = *(const float4*)&ss[col0 + jc * 16 + quad * 4];
        sh4[jc] = *(const float4*)&ss[128 + col0 + jc * 16 + quad * 4];
    }

    for (int ci = blockIdx.x; ci < NBUCK; ci += GG) {
        int row0 = ci * 128 + wm * 64;
        bf16x8 af[4][4];
#pragma unroll
        for (int kc = 0; kc < 4; ++kc)
#pragma unroll
            for (int ir = 0; ir < 4; ++ir)
                af[kc][ir] = *(const bf16x8*)&A[(size_t)(row0 + ir * 16 + l15) * 128 + kc * 32 + quad * 8];

        f32x4 acc[4][2];
#pragma unroll
        for (int ir = 0; ir < 4; ++ir)
#pragma unroll
            for (int jc = 0; jc < 2; ++jc) acc[ir][jc] = (f32x4){0.f, 0.f, 0.f, 0.f};

#pragma unroll
        for (int kc = 0; kc < 4; ++kc)
#pragma unroll
            for (int ir = 0; ir < 4; ++ir)
#pragma unroll
                for (int jc = 0; jc < 2; ++jc)
                    acc[ir][jc] = __builtin_amdgcn_mfma_f32_16x16x32_bf16(
                        bf_[kc][jc], af[kc][ir], acc[ir][jc], 0, 0, 0);

#pragma unroll
        for (int ir = 0; ir < 4; ++ir) {
            int row = row0 + ir * 16 + l15;
            if (row < N_NODES) {
#pragma unroll
                for (int jc = 0; jc < 2; ++jc) {
                    float4 v;
                    v.x = fmaxf(fmaf(acc[ir][jc][0], sc4[jc].x, sh4[jc].x), 0.f);
                    v.y = fmaxf(fmaf(acc[ir][jc][1], sc4[jc].y, sh4[jc].y), 0.f);
                    v.z = fmaxf(fmaf(acc[ir][jc][2], sc4[jc].z, sh4[jc].z), 0.f);
                    v.w = fmaxf(fmaf(acc[ir][jc][3], sc4[jc].w, sh4[jc].w), 0.f);
                    *(float4*)&out[(size_t)row * 128 + col0 + jc * 16 + quad * 4] = v;
                }
            }
        }
    }
}

extern "C" void kernel_launch(void* const* d_in, const int* in_sizes, int n_in,
                              void* d_out, int out_size, void* d_ws, size_t ws_size,
                              hipStream_t stream) {
    const float* x      = (const float*)d_in[0];
    const int*   eidx   = (const int*)d_in[1];
    const float* W      = (const float*)d_in[2];
    const float* skipW  = (const float*)d_in[4];
    const float* gamma  = (const float*)d_in[5];
    const float* beta   = (const float*)d_in[6];
    float* out = (float*)d_out;
    float* ws  = (float*)d_ws;

    const int* row = eidx;
    const int* col = eidx + E_EDGES;

    float* scaleshift = ws + OFF_SCALE;
    float* dinv       = ws + OFF_DINV;
    int*   rowptr     = (int*)(ws + OFF_ROWPTR);
    int*   base       = (int*)(ws + OFF_BASE);
    int*   gh_t       = (int*)(ws + OFF_GHIST);
    unsigned int* binned = (unsigned int*)(ws + OFF_BINNED);
    float* partial    = ws + OFF_PART;             // aliases binned (dead after agg)
    ushort* A         = (ushort*)(ws + OFF_A);
    unsigned* xd8     = (unsigned*)(ws + OFF_XD8);
    ushort* Bt        = (ushort*)(ws + OFF_BT);
    unsigned* tick    = (unsigned*)(ws + OFF_TICK);

    k_hist<<<NCHUNK + 64, 256, 0, stream>>>(col, gh_t, W, skipW, Bt, tick);
    k_scan<<<NBUCK_P / 4, 256, 0, stream>>>(gh_t, base, rowptr, tick);
    k_scatter_bin<<<NCHUNK, 256, 0, stream>>>(row, col, gh_t, base, binned);
    k_sortbucket<<<NBUCK, 256, 0, stream>>>(binned, base, rowptr, dinv, x, xd8, A);
    k_agg<<<(N_PAD * 16 + 255) / 256, 256, 0, stream>>>(xd8, dinv, rowptr, binned, A);
    k_gemm_stats<<<GG, 512, 0, stream>>>(A, Bt, partial);
    k_reduce<<<128, 256, 0, stream>>>(partial, gamma, beta, scaleshift);
    k_gemm_apply<<<GG, 512, 0, stream>>>(A, Bt, scaleshift, out);
}